// Round 7
// baseline (386.971 us; speedup 1.0000x reference)
//
#include <hip/hip_runtime.h>
#include <hip/hip_bf16.h>

#define D_DIM 128
#define N_ENT 100000
#define R_REL 8
#define E_EDGE 131072
#define B_HEAD 32768
#define NH_PAD 100352  // multiple of 256 >= N_ENT

typedef __attribute__((ext_vector_type(8))) short short8v;
typedef __attribute__((ext_vector_type(16))) float f32x16;
typedef unsigned int uint;
typedef unsigned short ushort;

union BF8 {
  short8v v;
  __hip_bfloat16 h[8];
};

__device__ inline ushort bfbits(float x) {
  union { __hip_bfloat16 h; ushort u; } c;
  c.h = __float2bfloat16(x);
  return c.u;
}
__device__ inline float bflo(uint p) { return __uint_as_float(p << 16); }
__device__ inline float bfhi(uint p) { return __uint_as_float(p & 0xffff0000u); }

// ---------- init: cnt_e = 0, inv = -1 ----------
__global__ __launch_bounds__(256) void init_ws(int* __restrict__ cnt_e,
                                               int* __restrict__ inv) {
  int i = blockIdx.x * 256 + threadIdx.x;  // grid covers R*NH_PAD
  if (i < R_REL * B_HEAD) cnt_e[i] = 0;
  inv[i] = -1;
}

// ---------- prep: tail -> bf16 image ----------
__global__ __launch_bounds__(256) void prep_tail(const float* __restrict__ tail,
                                                 short8v* __restrict__ tailb) {
  int i = blockIdx.x * 256 + threadIdx.x;  // 8-elem chunk id, 1.6M total
  const float4* s = (const float4*)tail + (size_t)i * 2;
  float4 a = s[0], b = s[1];
  BF8 h;
  h.h[0] = __float2bfloat16(a.x); h.h[1] = __float2bfloat16(a.y);
  h.h[2] = __float2bfloat16(a.z); h.h[3] = __float2bfloat16(a.w);
  h.h[4] = __float2bfloat16(b.x); h.h[5] = __float2bfloat16(b.y);
  h.h[6] = __float2bfloat16(b.z); h.h[7] = __float2bfloat16(b.w);
  tailb[i] = h.v;
}

// ---------- CSR build (edges) ----------
__global__ __launch_bounds__(256) void hist_edges(const int* __restrict__ erow,
                                                  int* __restrict__ cnt) {
  int r = blockIdx.y;
  int e = blockIdx.x * 256 + threadIdx.x;
  int row = erow[(size_t)r * E_EDGE + e];
  atomicAdd(cnt + r * B_HEAD + row, 1);
}

__global__ __launch_bounds__(256) void scan_blk(const int* __restrict__ cnt,
                                                int* __restrict__ cur,
                                                int* __restrict__ bsum) {
  int b = blockIdx.x, t = threadIdx.x;
  int4 v = ((const int4*)cnt)[b * 256 + t];
  int s = v.x + v.y + v.z + v.w;
  __shared__ int ps[256];
  ps[t] = s;
  __syncthreads();
  for (int off = 1; off < 256; off <<= 1) {
    int u = (t >= off) ? ps[t - off] : 0;
    __syncthreads();
    ps[t] += u;
    __syncthreads();
  }
  int base = ps[t] - s;
  int4 o;
  o.x = base; o.y = base + v.x; o.z = o.y + v.y; o.w = o.z + v.z;
  ((int4*)cur)[b * 256 + t] = o;
  if (t == 255) bsum[b] = ps[255];
}

__global__ __launch_bounds__(256) void scan_bsum(int* __restrict__ bsum) {
  int t = threadIdx.x;
  int s = bsum[t];
  __shared__ int ps[256];
  ps[t] = s;
  __syncthreads();
  for (int off = 1; off < 256; off <<= 1) {
    int u = (t >= off) ? ps[t - off] : 0;
    __syncthreads();
    ps[t] += u;
    __syncthreads();
  }
  bsum[t] = ps[t] - s;
}

__global__ __launch_bounds__(256) void scan_add(int* __restrict__ cur,
                                                const int* __restrict__ bsum) {
  int i = blockIdx.x * 256 + threadIdx.x;
  int o = bsum[i >> 8];
  int4 v = ((int4*)cur)[i];
  v.x += o; v.y += o; v.z += o; v.w += o;
  ((int4*)cur)[i] = v;
}

__global__ __launch_bounds__(256) void scatter_edges(const int* __restrict__ erow,
                                                     const int* __restrict__ ecol,
                                                     const float* __restrict__ ew,
                                                     int* __restrict__ cur,
                                                     int2* __restrict__ sColW) {
  int r = blockIdx.y;
  int e = blockIdx.x * 256 + threadIdx.x;
  size_t idx = (size_t)r * E_EDGE + e;
  int row = erow[idx];
  int pos = atomicAdd(cur + r * B_HEAD + row, 1);
  sColW[pos] = make_int2(ecol[idx], __float_as_int(ew[idx]));
}

// inv[r][head[r][i]] = i  (head entries unique per relation -> race-free)
__global__ __launch_bounds__(256) void build_inv(const int* __restrict__ head,
                                                 int* __restrict__ inv) {
  int i = blockIdx.x * 256 + threadIdx.x;  // 0..R*B
  int r = i >> 15;                         // B = 32768
  inv[r * NH_PAD + head[i]] = i & (B_HEAD - 1);
}

// ---------- aggregation: one wave per (r,row); bf16 gather, bf16 agg out ----------
__global__ __launch_bounds__(256) void csr_agg(const uint* __restrict__ tailb,
                                               const int* __restrict__ end_e,
                                               const int* __restrict__ cnt_e,
                                               const int2* __restrict__ sColW,
                                               uint* __restrict__ aggb, int r0) {
  int wid = (blockIdx.x << 2) + (threadIdx.x >> 6);  // chunk-local row id
  int lane = threadIdx.x & 63;
  int f = r0 * B_HEAD + wid;
  int cn = cnt_e[f];
  int s = end_e[f] - cn;
  float ax = 0.f, ay = 0.f, bx = 0.f, by = 0.f;
  int k = 0;
  for (; k + 2 <= cn; k += 2) {
    int2 e0 = sColW[s + k];
    int2 e1 = sColW[s + k + 1];
    uint t0 = tailb[(size_t)e0.x * 64 + lane];
    uint t1 = tailb[(size_t)e1.x * 64 + lane];
    float w0 = __int_as_float(e0.y), w1 = __int_as_float(e1.y);
    ax += w0 * bflo(t0); ay += w0 * bfhi(t0);
    bx += w1 * bflo(t1); by += w1 * bfhi(t1);
  }
  if (k < cn) {
    int2 e0 = sColW[s + k];
    uint t0 = tailb[(size_t)e0.x * 64 + lane];
    float w0 = __int_as_float(e0.y);
    ax += w0 * bflo(t0); ay += w0 * bfhi(t0);
  }
  ax += bx; ay += by;
  aggb[(size_t)wid * 64 + lane] = (uint)bfbits(ax) | ((uint)bfbits(ay) << 16);
}

// ---------- W prep: hi/lo bf16 slot-major images ----------
// out[n][o] = sum_i A[n][i]*M[i][o]; mat0: M=W^T, mat1+r: M=relW[r].
__global__ __launch_bounds__(256) void prep_W(const float* __restrict__ W,
                                              const float* __restrict__ relW,
                                              short8v* __restrict__ WhS,
                                              short8v* __restrict__ WlS) {
  int mat = blockIdx.y;
  int idx = blockIdx.x * 256 + threadIdx.x;  // 0..2047
  int o = idx & 127, ks = idx >> 7;
  float v[8];
  if (mat == 0) {
    const float* src = W + o * D_DIM + ks * 8;
#pragma unroll
    for (int j = 0; j < 8; ++j) v[j] = src[j];
  } else {
    const float* src = relW + (size_t)(mat - 1) * D_DIM * D_DIM + (ks * 8) * D_DIM + o;
#pragma unroll
    for (int j = 0; j < 8; ++j) v[j] = src[j * D_DIM];
  }
  BF8 h, l;
#pragma unroll
  for (int j = 0; j < 8; ++j) {
    __hip_bfloat16 hb = __float2bfloat16(v[j]);
    h.h[j] = hb;
    l.h[j] = __float2bfloat16(v[j] - __bfloat162float(hb));
  }
  WhS[(size_t)mat * 2048 + idx] = h.v;
  WlS[(size_t)mat * 2048 + idx] = l.v;
}

// ---------- rel GEMM: upd_bf16[row][o] = sum_i aggb[row][i]*relW[i][o] ----------
// A direct bf16 fragments (no cvt), B split hi/lo -> 2 MFMA per step.
__global__ __launch_bounds__(256) void gemm_rel(const ushort* __restrict__ aggb,
                                                const short8v* __restrict__ WhS,
                                                const short8v* __restrict__ WlS,
                                                ushort* __restrict__ updb, int r0) {
  __shared__ short8v wlds[2][8][128];  // 32 KB
  int tid = threadIdx.x;
  int kk_rel = blockIdx.y;
  int mat = 1 + r0 + kk_rel;
  const short8v* Hsrc = WhS + (size_t)mat * 2048;
  const short8v* Lsrc = WlS + (size_t)mat * 2048;
  int w = tid >> 6, lane = tid & 63, lrow = lane & 31, lsel = lane >> 5;
  int arow = blockIdx.x * 128 + w * 32 + lrow;
  const short8v* Arow =
      (const short8v*)(aggb + ((size_t)kk_rel * B_HEAD + arow) * D_DIM);

  f32x16 acc[4] = {};
  for (int half = 0; half < 2; ++half) {
    if (half) __syncthreads();
#pragma unroll
    for (int it = 0; it < 4; ++it) {
      int e = it * 256 + tid;
      wlds[0][e >> 7][e & 127] = Hsrc[half * 1024 + e];
      wlds[1][e >> 7][e & 127] = Lsrc[half * 1024 + e];
    }
    __syncthreads();
#pragma unroll
    for (int kk = 0; kk < 4; ++kk) {
      short8v a = Arow[half * 8 + kk * 2 + lsel];
      int ks = kk * 2 + lsel;
#pragma unroll
      for (int n = 0; n < 4; ++n) {
        short8v bh = wlds[0][ks][n * 32 + lrow];
        short8v bl = wlds[1][ks][n * 32 + lrow];
        acc[n] = __builtin_amdgcn_mfma_f32_32x32x16_bf16(a, bh, acc[n], 0, 0, 0);
        acc[n] = __builtin_amdgcn_mfma_f32_32x32x16_bf16(a, bl, acc[n], 0, 0, 0);
      }
    }
  }
  int wrow0 = blockIdx.x * 128 + w * 32;
#pragma unroll
  for (int reg = 0; reg < 16; ++reg) {
    int srow = wrow0 + (reg & 3) + 8 * (reg >> 2) + 4 * lsel;
    ushort* urow = updb + ((size_t)kk_rel * B_HEAD + srow) * D_DIM;
#pragma unroll
    for (int n = 0; n < 4; ++n) urow[n * 32 + lrow] = bfbits(acc[n][reg]);
  }
}

// ---------- x GEMM (split-bf16 A and B), optional fused upd-add + relu ----------
template <bool FUSE>
__global__ __launch_bounds__(256) void gemm_x(const float* __restrict__ A,
                                              const short8v* __restrict__ WhS,
                                              const short8v* __restrict__ WlS,
                                              const int* __restrict__ inv,
                                              const ushort* __restrict__ updb,
                                              float* __restrict__ Out, int nrows) {
  __shared__ short8v wlds[2][8][128];  // 32 KB
  int tid = threadIdx.x;
  int w = tid >> 6, lane = tid & 63, lrow = lane & 31, lsel = lane >> 5;
  int arow = blockIdx.x * 128 + w * 32 + lrow;
  int arowc = (arow < nrows) ? arow : (nrows - 1);
  const float4* Arow = (const float4*)(A + (size_t)arowc * D_DIM);

  f32x16 acc[4] = {};
  for (int half = 0; half < 2; ++half) {
    if (half) __syncthreads();
#pragma unroll
    for (int it = 0; it < 4; ++it) {
      int e = it * 256 + tid;
      wlds[0][e >> 7][e & 127] = WhS[half * 1024 + e];
      wlds[1][e >> 7][e & 127] = WlS[half * 1024 + e];
    }
    __syncthreads();
#pragma unroll
    for (int kk = 0; kk < 4; ++kk) {
      int k0 = half * 64 + kk * 16;
      float4 a0 = Arow[(k0 >> 2) + lsel * 2];
      float4 a1 = Arow[(k0 >> 2) + lsel * 2 + 1];
      float av[8] = {a0.x, a0.y, a0.z, a0.w, a1.x, a1.y, a1.z, a1.w};
      BF8 ah, al;
#pragma unroll
      for (int j = 0; j < 8; ++j) {
        __hip_bfloat16 hb = __float2bfloat16(av[j]);
        ah.h[j] = hb;
        al.h[j] = __float2bfloat16(av[j] - __bfloat162float(hb));
      }
      int ks = kk * 2 + lsel;
#pragma unroll
      for (int n = 0; n < 4; ++n) {
        short8v bh = wlds[0][ks][n * 32 + lrow];
        short8v bl = wlds[1][ks][n * 32 + lrow];
        acc[n] = __builtin_amdgcn_mfma_f32_32x32x16_bf16(ah.v, bh, acc[n], 0, 0, 0);
        acc[n] = __builtin_amdgcn_mfma_f32_32x32x16_bf16(ah.v, bl, acc[n], 0, 0, 0);
        acc[n] = __builtin_amdgcn_mfma_f32_32x32x16_bf16(al.v, bh, acc[n], 0, 0, 0);
        acc[n] = __builtin_amdgcn_mfma_f32_32x32x16_bf16(al.v, bl, acc[n], 0, 0, 0);
      }
    }
  }
  int wrow0 = blockIdx.x * 128 + w * 32;
#pragma unroll
  for (int reg = 0; reg < 16; ++reg) {
    int srow = wrow0 + (reg & 3) + 8 * (reg >> 2) + 4 * lsel;
    if (srow < nrows) {
      float vals[4];
#pragma unroll
      for (int n = 0; n < 4; ++n) vals[n] = acc[n][reg];
      if (FUSE) {
#pragma unroll
        for (int r = 0; r < R_REL; ++r) {
          int row = inv[r * NH_PAD + srow];
          if (row >= 0) {
            const ushort* u = updb + ((size_t)r * B_HEAD + row) * D_DIM;
#pragma unroll
            for (int n = 0; n < 4; ++n)
              vals[n] += __uint_as_float((uint)u[n * 32 + lrow] << 16);
          }
        }
#pragma unroll
        for (int n = 0; n < 4; ++n) vals[n] = fmaxf(vals[n], 0.f);
      }
      float* orow = Out + (size_t)srow * D_DIM;
#pragma unroll
      for (int n = 0; n < 4; ++n) orow[n * 32 + lrow] = vals[n];
    }
  }
}

// fallback: out[n] += upd rows (bf16) of relations [r0, r0+c); optional relu.
__global__ __launch_bounds__(256) void final_add(const int* __restrict__ inv,
                                                 const ushort* __restrict__ updb,
                                                 float* __restrict__ out, int r0,
                                                 int c, int doRelu) {
  int n = blockIdx.x * 8 + (threadIdx.x >> 5);
  int lane = threadIdx.x & 31;
  if (n >= N_ENT) return;
  float4* o4 = (float4*)out + (size_t)n * 32 + lane;
  float4 v = *o4;
  for (int k = 0; k < c; ++k) {
    int row = inv[(r0 + k) * NH_PAD + n];
    if (row >= 0) {
      uint2 u = ((const uint2*)updb)[((size_t)k * B_HEAD + row) * 32 + lane];
      v.x += bflo(u.x); v.y += bfhi(u.x);
      v.z += bflo(u.y); v.w += bfhi(u.y);
    }
  }
  if (doRelu) {
    v.x = fmaxf(v.x, 0.f); v.y = fmaxf(v.y, 0.f);
    v.z = fmaxf(v.z, 0.f); v.w = fmaxf(v.w, 0.f);
  }
  *o4 = v;
}

extern "C" void kernel_launch(void* const* d_in, const int* in_sizes, int n_in,
                              void* d_out, int out_size, void* d_ws, size_t ws_size,
                              hipStream_t stream) {
  const float* x = (const float*)d_in[0];
  const float* tail = (const float*)d_in[1];
  const float* W = (const float*)d_in[2];
  const float* relW = (const float*)d_in[3];
  const float* ew = (const float*)d_in[4];
  const int* erow = (const int*)d_in[5];
  const int* ecol = (const int*)d_in[6];
  const int* head = (const int*)d_in[7];
  float* out = (float*)d_out;

  // ws layout (16B-aligned chunks):
  char* p = (char*)d_ws;
  short8v* WhS = (short8v*)p;  p += (size_t)(R_REL + 1) * 2048 * 16;
  short8v* WlS = (short8v*)p;  p += (size_t)(R_REL + 1) * 2048 * 16;
  short8v* tailb = (short8v*)p; p += (size_t)N_ENT * D_DIM * 2;
  int* cnt_e = (int*)p;        p += (size_t)R_REL * B_HEAD * 4;
  int* cur_e = (int*)p;        p += (size_t)R_REL * B_HEAD * 4;  // becomes end_e
  int* inv = (int*)p;          p += (size_t)R_REL * NH_PAD * 4;
  int* bsum = (int*)p;         p += 256 * 4;
  int2* sColW = (int2*)p;      p += (size_t)R_REL * E_EDGE * 8;
  char* dyn = p;  // aggb (chunk*B*128*2) + updb (chunk*B*128*2)
  size_t fixed = (size_t)(p - (char*)d_ws);
  size_t per_rel = (size_t)B_HEAD * D_DIM * 2 * 2;  // aggb + updb, bf16
  size_t avail = (ws_size > fixed) ? ws_size - fixed : 0;
  int chunk = (int)(avail / per_rel);
  if (chunk > R_REL) chunk = R_REL;
  if (chunk < 1) chunk = 1;
  ushort* aggb = (ushort*)dyn;
  ushort* updb = (ushort*)(dyn + (size_t)chunk * B_HEAD * D_DIM * 2);

  init_ws<<<dim3(R_REL * NH_PAD / 256), 256, 0, stream>>>(cnt_e, inv);
  prep_W<<<dim3(8, R_REL + 1), 256, 0, stream>>>(W, relW, WhS, WlS);
  prep_tail<<<dim3(N_ENT * D_DIM / 8 / 256), 256, 0, stream>>>(tail, tailb);

  hist_edges<<<dim3(E_EDGE / 256, R_REL), 256, 0, stream>>>(erow, cnt_e);
  scan_blk<<<dim3(256), 256, 0, stream>>>(cnt_e, cur_e, bsum);
  scan_bsum<<<dim3(1), 256, 0, stream>>>(bsum);
  scan_add<<<dim3(256), 256, 0, stream>>>(cur_e, bsum);
  scatter_edges<<<dim3(E_EDGE / 256, R_REL), 256, 0, stream>>>(erow, ecol, ew, cur_e,
                                                               sColW);
  build_inv<<<dim3(R_REL * B_HEAD / 256), 256, 0, stream>>>(head, inv);

  if (chunk == R_REL) {
    // single pass: all upd ready, fold into gemm_x epilogue
    csr_agg<<<dim3(R_REL * B_HEAD / 4), 256, 0, stream>>>(
        (const uint*)tailb, cur_e, cnt_e, sColW, (uint*)aggb, 0);
    gemm_rel<<<dim3(B_HEAD / 128, R_REL), 256, 0, stream>>>(aggb, WhS, WlS, updb, 0);
    gemm_x<true><<<dim3((N_ENT + 127) / 128), 256, 0, stream>>>(x, WhS, WlS, inv,
                                                                updb, out, N_ENT);
  } else {
    gemm_x<false><<<dim3((N_ENT + 127) / 128), 256, 0, stream>>>(x, WhS, WlS, inv,
                                                                 updb, out, N_ENT);
    for (int r0 = 0; r0 < R_REL; r0 += chunk) {
      int c = (R_REL - r0 < chunk) ? (R_REL - r0) : chunk;
      csr_agg<<<dim3(c * B_HEAD / 4), 256, 0, stream>>>(
          (const uint*)tailb, cur_e, cnt_e, sColW, (uint*)aggb, r0);
      gemm_rel<<<dim3(B_HEAD / 128, c), 256, 0, stream>>>(aggb, WhS, WlS, updb, r0);
      final_add<<<dim3((N_ENT + 7) / 8), 256, 0, stream>>>(inv, updb, out, r0, c,
                                                           (r0 + c == R_REL) ? 1 : 0);
    }
  }
}

// Round 8
// 329.160 us; speedup vs baseline: 1.1756x; 1.1756x over previous
//
#include <hip/hip_runtime.h>
#include <hip/hip_bf16.h>

#define D_DIM 128
#define N_ENT 100000
#define R_REL 8
#define E_EDGE 131072
#define B_HEAD 32768
#define NH_PAD 100352  // multiple of 256 >= N_ENT

typedef __attribute__((ext_vector_type(8))) short short8v;
typedef __attribute__((ext_vector_type(16))) float f32x16;
typedef unsigned int uint;
typedef unsigned short ushort;

union BF8 {
  short8v v;
  __hip_bfloat16 h[8];
};

__device__ inline ushort bfbits(float x) {
  union { __hip_bfloat16 h; ushort u; } c;
  c.h = __float2bfloat16(x);
  return c.u;
}
__device__ inline float bflo(uint p) { return __uint_as_float(p << 16); }
__device__ inline float bfhi(uint p) { return __uint_as_float(p & 0xffff0000u); }

// ---------- init: cnt_e = 0, inv = -1 ----------
__global__ __launch_bounds__(256) void init_ws(int* __restrict__ cnt_e,
                                               int* __restrict__ inv) {
  int i = blockIdx.x * 256 + threadIdx.x;  // grid covers R*NH_PAD
  if (i < R_REL * B_HEAD) cnt_e[i] = 0;
  inv[i] = -1;
}

// ---------- prep: f32 matrix -> bf16 image (grid covers count/8 elems) ----------
__global__ __launch_bounds__(256) void prep_bf16(const float* __restrict__ src,
                                                 short8v* __restrict__ dst) {
  int i = blockIdx.x * 256 + threadIdx.x;  // 8-elem chunk id
  const float4* s = (const float4*)src + (size_t)i * 2;
  float4 a = s[0], b = s[1];
  BF8 h;
  h.h[0] = __float2bfloat16(a.x); h.h[1] = __float2bfloat16(a.y);
  h.h[2] = __float2bfloat16(a.z); h.h[3] = __float2bfloat16(a.w);
  h.h[4] = __float2bfloat16(b.x); h.h[5] = __float2bfloat16(b.y);
  h.h[6] = __float2bfloat16(b.z); h.h[7] = __float2bfloat16(b.w);
  dst[i] = h.v;
}

// ---------- CSR build (edges) ----------
__global__ __launch_bounds__(256) void hist_edges(const int* __restrict__ erow,
                                                  int* __restrict__ cnt) {
  int r = blockIdx.y;
  int e = blockIdx.x * 256 + threadIdx.x;
  int row = erow[(size_t)r * E_EDGE + e];
  atomicAdd(cnt + r * B_HEAD + row, 1);
}

__global__ __launch_bounds__(256) void scan_blk(const int* __restrict__ cnt,
                                                int* __restrict__ cur,
                                                int* __restrict__ bsum) {
  int b = blockIdx.x, t = threadIdx.x;
  int4 v = ((const int4*)cnt)[b * 256 + t];
  int s = v.x + v.y + v.z + v.w;
  __shared__ int ps[256];
  ps[t] = s;
  __syncthreads();
  for (int off = 1; off < 256; off <<= 1) {
    int u = (t >= off) ? ps[t - off] : 0;
    __syncthreads();
    ps[t] += u;
    __syncthreads();
  }
  int base = ps[t] - s;
  int4 o;
  o.x = base; o.y = base + v.x; o.z = o.y + v.y; o.w = o.z + v.z;
  ((int4*)cur)[b * 256 + t] = o;
  if (t == 255) bsum[b] = ps[255];
}

__global__ __launch_bounds__(256) void scan_bsum(int* __restrict__ bsum) {
  int t = threadIdx.x;
  int s = bsum[t];
  __shared__ int ps[256];
  ps[t] = s;
  __syncthreads();
  for (int off = 1; off < 256; off <<= 1) {
    int u = (t >= off) ? ps[t - off] : 0;
    __syncthreads();
    ps[t] += u;
    __syncthreads();
  }
  bsum[t] = ps[t] - s;
}

__global__ __launch_bounds__(256) void scan_add(int* __restrict__ cur,
                                                const int* __restrict__ bsum) {
  int i = blockIdx.x * 256 + threadIdx.x;
  int o = bsum[i >> 8];
  int4 v = ((int4*)cur)[i];
  v.x += o; v.y += o; v.z += o; v.w += o;
  ((int4*)cur)[i] = v;
}

__global__ __launch_bounds__(256) void scatter_edges(const int* __restrict__ erow,
                                                     const int* __restrict__ ecol,
                                                     const float* __restrict__ ew,
                                                     int* __restrict__ cur,
                                                     int2* __restrict__ sColW) {
  int r = blockIdx.y;
  int e = blockIdx.x * 256 + threadIdx.x;
  size_t idx = (size_t)r * E_EDGE + e;
  int row = erow[idx];
  int pos = atomicAdd(cur + r * B_HEAD + row, 1);
  sColW[pos] = make_int2(ecol[idx], __float_as_int(ew[idx]));
}

// inv[r][head[r][i]] = i  (head entries unique per relation -> race-free)
__global__ __launch_bounds__(256) void build_inv(const int* __restrict__ head,
                                                 int* __restrict__ inv) {
  int i = blockIdx.x * 256 + threadIdx.x;  // 0..R*B
  int r = i >> 15;                         // B = 32768
  inv[r * NH_PAD + head[i]] = i & (B_HEAD - 1);
}

// ---------- aggregation: one wave per (r,row); bf16 gather, bf16 agg out ----------
__global__ __launch_bounds__(256) void csr_agg(const uint* __restrict__ tailb,
                                               const int* __restrict__ end_e,
                                               const int* __restrict__ cnt_e,
                                               const int2* __restrict__ sColW,
                                               uint* __restrict__ aggb, int r0) {
  int wid = (blockIdx.x << 2) + (threadIdx.x >> 6);  // chunk-local row id
  int lane = threadIdx.x & 63;
  int f = r0 * B_HEAD + wid;
  int cn = cnt_e[f];
  int s = end_e[f] - cn;
  float ax = 0.f, ay = 0.f, bx = 0.f, by = 0.f;
  int k = 0;
  for (; k + 2 <= cn; k += 2) {
    int2 e0 = sColW[s + k];
    int2 e1 = sColW[s + k + 1];
    uint t0 = tailb[(size_t)e0.x * 64 + lane];
    uint t1 = tailb[(size_t)e1.x * 64 + lane];
    float w0 = __int_as_float(e0.y), w1 = __int_as_float(e1.y);
    ax += w0 * bflo(t0); ay += w0 * bfhi(t0);
    bx += w1 * bflo(t1); by += w1 * bfhi(t1);
  }
  if (k < cn) {
    int2 e0 = sColW[s + k];
    uint t0 = tailb[(size_t)e0.x * 64 + lane];
    float w0 = __int_as_float(e0.y);
    ax += w0 * bflo(t0); ay += w0 * bfhi(t0);
  }
  ax += bx; ay += by;
  aggb[(size_t)wid * 64 + lane] = (uint)bfbits(ax) | ((uint)bfbits(ay) << 16);
}

// ---------- W prep: hi/lo bf16 slot-major images ----------
// out[n][o] = sum_i A[n][i]*M[i][o]; mat0: M=W^T, mat1+r: M=relW[r].
__global__ __launch_bounds__(256) void prep_W(const float* __restrict__ W,
                                              const float* __restrict__ relW,
                                              short8v* __restrict__ WhS,
                                              short8v* __restrict__ WlS) {
  int mat = blockIdx.y;
  int idx = blockIdx.x * 256 + threadIdx.x;  // 0..2047
  int o = idx & 127, ks = idx >> 7;
  float v[8];
  if (mat == 0) {
    const float* src = W + o * D_DIM + ks * 8;
#pragma unroll
    for (int j = 0; j < 8; ++j) v[j] = src[j];
  } else {
    const float* src = relW + (size_t)(mat - 1) * D_DIM * D_DIM + (ks * 8) * D_DIM + o;
#pragma unroll
    for (int j = 0; j < 8; ++j) v[j] = src[j * D_DIM];
  }
  BF8 h, l;
#pragma unroll
  for (int j = 0; j < 8; ++j) {
    __hip_bfloat16 hb = __float2bfloat16(v[j]);
    h.h[j] = hb;
    l.h[j] = __float2bfloat16(v[j] - __bfloat162float(hb));
  }
  WhS[(size_t)mat * 2048 + idx] = h.v;
  WlS[(size_t)mat * 2048 + idx] = l.v;
}

// ---------- unified GEMM: blocks [0,nxb) -> x@W^T (f32 out),
// blocks [nxb, nxb+256*c) -> per-relation aggb@relW (bf16 updb out). ----------
__global__ __launch_bounds__(256) void gemm_all(const ushort* __restrict__ xb,
                                                const ushort* __restrict__ aggb,
                                                const short8v* __restrict__ WhS,
                                                const short8v* __restrict__ WlS,
                                                float* __restrict__ out,
                                                ushort* __restrict__ updb, int r0,
                                                int nxb) {
  __shared__ short8v wlds[2][8][128];  // 32 KB
  int tid = threadIdx.x;
  int bid = blockIdx.x;
  bool xpart = (bid < nxb);
  const ushort* Abase;
  int mat, rowbase, relloc = 0;
  if (xpart) {
    Abase = xb;
    mat = 0;
    rowbase = bid * 128;
  } else {
    int b = bid - nxb;
    relloc = b >> 8;
    mat = 1 + r0 + relloc;
    rowbase = (b & 255) * 128;
    Abase = aggb + (size_t)relloc * B_HEAD * D_DIM;
  }
  const short8v* Hsrc = WhS + (size_t)mat * 2048;
  const short8v* Lsrc = WlS + (size_t)mat * 2048;
  int w = tid >> 6, lane = tid & 63, lrow = lane & 31, lsel = lane >> 5;
  int nrows = xpart ? N_ENT : B_HEAD;
  int arow = rowbase + w * 32 + lrow;
  int arowc = (arow < nrows) ? arow : (nrows - 1);
  const short8v* Arow = (const short8v*)(Abase + (size_t)arowc * D_DIM);

  f32x16 acc[4] = {};
  for (int half = 0; half < 2; ++half) {
    if (half) __syncthreads();
#pragma unroll
    for (int it = 0; it < 4; ++it) {
      int e = it * 256 + tid;
      wlds[0][e >> 7][e & 127] = Hsrc[half * 1024 + e];
      wlds[1][e >> 7][e & 127] = Lsrc[half * 1024 + e];
    }
    __syncthreads();
#pragma unroll
    for (int kk = 0; kk < 4; ++kk) {
      short8v a = Arow[half * 8 + kk * 2 + lsel];
      int ks = kk * 2 + lsel;
#pragma unroll
      for (int n = 0; n < 4; ++n) {
        short8v bh = wlds[0][ks][n * 32 + lrow];
        short8v bl = wlds[1][ks][n * 32 + lrow];
        acc[n] = __builtin_amdgcn_mfma_f32_32x32x16_bf16(a, bh, acc[n], 0, 0, 0);
        acc[n] = __builtin_amdgcn_mfma_f32_32x32x16_bf16(a, bl, acc[n], 0, 0, 0);
      }
    }
  }
  int wrow0 = rowbase + w * 32;
  if (xpart) {
#pragma unroll
    for (int reg = 0; reg < 16; ++reg) {
      int srow = wrow0 + (reg & 3) + 8 * (reg >> 2) + 4 * lsel;
      if (srow < N_ENT) {
        float* orow = out + (size_t)srow * D_DIM;
#pragma unroll
        for (int n = 0; n < 4; ++n) orow[n * 32 + lrow] = acc[n][reg];
      }
    }
  } else {
    ushort* ubase = updb + (size_t)relloc * B_HEAD * D_DIM;
#pragma unroll
    for (int reg = 0; reg < 16; ++reg) {
      int srow = wrow0 + (reg & 3) + 8 * (reg >> 2) + 4 * lsel;
      ushort* urow = ubase + (size_t)srow * D_DIM;
#pragma unroll
      for (int n = 0; n < 4; ++n) urow[n * 32 + lrow] = bfbits(acc[n][reg]);
    }
  }
}

// out[n] += upd rows (bf16) of relations [r0, r0+c); optional relu.
__global__ __launch_bounds__(256) void final_add(const int* __restrict__ inv,
                                                 const ushort* __restrict__ updb,
                                                 float* __restrict__ out, int r0,
                                                 int c, int doRelu) {
  int n = blockIdx.x * 8 + (threadIdx.x >> 5);
  int lane = threadIdx.x & 31;
  if (n >= N_ENT) return;
  float4* o4 = (float4*)out + (size_t)n * 32 + lane;
  float4 v = *o4;
  for (int k = 0; k < c; ++k) {
    int row = inv[(r0 + k) * NH_PAD + n];
    if (row >= 0) {
      uint2 u = ((const uint2*)updb)[((size_t)k * B_HEAD + row) * 32 + lane];
      v.x += bflo(u.x); v.y += bfhi(u.x);
      v.z += bflo(u.y); v.w += bfhi(u.y);
    }
  }
  if (doRelu) {
    v.x = fmaxf(v.x, 0.f); v.y = fmaxf(v.y, 0.f);
    v.z = fmaxf(v.z, 0.f); v.w = fmaxf(v.w, 0.f);
  }
  *o4 = v;
}

extern "C" void kernel_launch(void* const* d_in, const int* in_sizes, int n_in,
                              void* d_out, int out_size, void* d_ws, size_t ws_size,
                              hipStream_t stream) {
  const float* x = (const float*)d_in[0];
  const float* tail = (const float*)d_in[1];
  const float* W = (const float*)d_in[2];
  const float* relW = (const float*)d_in[3];
  const float* ew = (const float*)d_in[4];
  const int* erow = (const int*)d_in[5];
  const int* ecol = (const int*)d_in[6];
  const int* head = (const int*)d_in[7];
  float* out = (float*)d_out;

  // ws layout (16B-aligned chunks):
  char* p = (char*)d_ws;
  short8v* WhS = (short8v*)p;   p += (size_t)(R_REL + 1) * 2048 * 16;
  short8v* WlS = (short8v*)p;   p += (size_t)(R_REL + 1) * 2048 * 16;
  short8v* tailb = (short8v*)p; p += (size_t)N_ENT * D_DIM * 2;
  short8v* xb = (short8v*)p;    p += (size_t)N_ENT * D_DIM * 2;
  int* cnt_e = (int*)p;         p += (size_t)R_REL * B_HEAD * 4;
  int* cur_e = (int*)p;         p += (size_t)R_REL * B_HEAD * 4;  // becomes end_e
  int* inv = (int*)p;           p += (size_t)R_REL * NH_PAD * 4;
  int* bsum = (int*)p;          p += 256 * 4;
  int2* sColW = (int2*)p;       p += (size_t)R_REL * E_EDGE * 8;
  char* dyn = p;  // aggb (chunk*B*128*2) + updb (chunk*B*128*2)
  size_t fixed = (size_t)(p - (char*)d_ws);
  size_t per_rel = (size_t)B_HEAD * D_DIM * 2 * 2;  // aggb + updb, bf16
  size_t avail = (ws_size > fixed) ? ws_size - fixed : 0;
  int chunk = (int)(avail / per_rel);
  if (chunk > R_REL) chunk = R_REL;
  if (chunk < 1) chunk = 1;
  ushort* aggb = (ushort*)dyn;
  ushort* updb = (ushort*)(dyn + (size_t)chunk * B_HEAD * D_DIM * 2);

  const int NXB = (N_ENT + 127) / 128;  // 782

  init_ws<<<dim3(R_REL * NH_PAD / 256), 256, 0, stream>>>(cnt_e, inv);
  prep_W<<<dim3(8, R_REL + 1), 256, 0, stream>>>(W, relW, WhS, WlS);
  prep_bf16<<<dim3(N_ENT * D_DIM / 8 / 256), 256, 0, stream>>>(tail, tailb);
  prep_bf16<<<dim3(N_ENT * D_DIM / 8 / 256), 256, 0, stream>>>(x, xb);

  hist_edges<<<dim3(E_EDGE / 256, R_REL), 256, 0, stream>>>(erow, cnt_e);
  scan_blk<<<dim3(256), 256, 0, stream>>>(cnt_e, cur_e, bsum);
  scan_bsum<<<dim3(1), 256, 0, stream>>>(bsum);
  scan_add<<<dim3(256), 256, 0, stream>>>(cur_e, bsum);
  scatter_edges<<<dim3(E_EDGE / 256, R_REL), 256, 0, stream>>>(erow, ecol, ew, cur_e,
                                                               sColW);
  build_inv<<<dim3(R_REL * B_HEAD / 256), 256, 0, stream>>>(head, inv);

  for (int r0 = 0; r0 < R_REL; r0 += chunk) {
    int c = (R_REL - r0 < chunk) ? (R_REL - r0) : chunk;
    csr_agg<<<dim3(c * B_HEAD / 4), 256, 0, stream>>>(
        (const uint*)tailb, cur_e, cnt_e, sColW, (uint*)aggb, r0);
    int nxb = (r0 == 0) ? NXB : 0;  // fold the x-GEMM into the first chunk's dispatch
    gemm_all<<<dim3(nxb + 256 * c), 256, 0, stream>>>(
        (const ushort*)xb, aggb, WhS, WlS, out, updb, r0, nxb);
    final_add<<<dim3((N_ENT + 7) / 8), 256, 0, stream>>>(inv, updb, out, r0, c,
                                                         (r0 + c == R_REL) ? 1 : 0);
  }
}